// Round 11
// baseline (90.066 us; speedup 1.0000x reference)
//
#include <hip/hip_runtime.h>
#include <hip/hip_bf16.h>

#define NB 2
#define NQS 1024
#define NKS 1024
#define DD 512
#define HH 32
#define NKROW (NB * NKS)  // 2048 key rows; query rows follow in E
#define W1S 34            // LDS stride: conflict-free B-frag reads

typedef __attribute__((ext_vector_type(8))) short bf16x8;
typedef __attribute__((ext_vector_type(4))) float f32x4;

static __device__ __forceinline__ float fexp2(float x) {
#if __has_builtin(__builtin_amdgcn_exp2f)
  return __builtin_amdgcn_exp2f(x);
#else
  float r; asm("v_exp_f32 %0, %1" : "=v"(r) : "v"(x)); return r;
#endif
}
static __device__ __forceinline__ float frcp(float x) {
#if __has_builtin(__builtin_amdgcn_rcpf)
  return __builtin_amdgcn_rcpf(x);
#else
  float r; asm("v_rcp_f32 %0, %1" : "=v"(r) : "v"(x)); return r;
#endif
}
// readfirstlane preserving float bits (builtin is int-typed)
static __device__ __forceinline__ float rfl_f32(float x) {
  return __int_as_float(__builtin_amdgcn_readfirstlane(__float_as_int(x)));
}

// ---------------- p1 body (R9, unchanged) ----------------
static __device__ __forceinline__ void p1_body(
    const float* __restrict__ keys, const float* __restrict__ queries,
    const float* __restrict__ W1, const float* __restrict__ b1,
    float* __restrict__ E, int row0) {
  __shared__ __hip_bfloat16 W1L[DD * W1S];
  __shared__ float red[4 * 2 * 64 * 4];  // [wave][ntile][lane][reg]
  const float S = 2.8853900817779268f;   // 2*log2(e)
  const int tid = threadIdx.x;
  const bool isq = row0 >= NKROW;
  const float* src = isq ? queries + (size_t)(row0 - NKROW) * DD
                         : keys + (size_t)row0 * DD;
  const float* w1 = W1 + (isq ? (size_t)DD * HH : 0);
#pragma unroll
  for (int s = 0; s < 16; ++s) {
    const int f = tid + s * 256;
    float4 v = *(const float4*)(w1 + (size_t)f * 4);
    const int k = f >> 3, h0 = (f & 7) * 4;
    __hip_bfloat16* p = &W1L[k * W1S + h0];
    p[0] = __float2bfloat16(v.x); p[1] = __float2bfloat16(v.y);
    p[2] = __float2bfloat16(v.z); p[3] = __float2bfloat16(v.w);
  }
  __syncthreads();
  const int l = tid & 63, w = tid >> 6;
  const int m = l & 15, kq = l >> 4;
  f32x4 acc0 = {0.f, 0.f, 0.f, 0.f}, acc1 = {0.f, 0.f, 0.f, 0.f};
  const float* arow = src + (size_t)m * DD + w * 128 + kq * 8;
  union Frag { bf16x8 v; __hip_bfloat16 e[8]; };
#pragma unroll
  for (int s = 0; s < 4; ++s) {
    const int kb = w * 128 + s * 32;
    float4 a0 = *(const float4*)(arow + s * 32);
    float4 a1 = *(const float4*)(arow + s * 32 + 4);
    Frag af, bf0, bf1;
    af.e[0] = __float2bfloat16(a0.x); af.e[1] = __float2bfloat16(a0.y);
    af.e[2] = __float2bfloat16(a0.z); af.e[3] = __float2bfloat16(a0.w);
    af.e[4] = __float2bfloat16(a1.x); af.e[5] = __float2bfloat16(a1.y);
    af.e[6] = __float2bfloat16(a1.z); af.e[7] = __float2bfloat16(a1.w);
    const __hip_bfloat16* bp = &W1L[(kb + kq * 8) * W1S + m];
#pragma unroll
    for (int j = 0; j < 8; ++j) {
      bf0.e[j] = bp[j * W1S];
      bf1.e[j] = bp[j * W1S + 16];
    }
    acc0 = __builtin_amdgcn_mfma_f32_16x16x32_bf16(af.v, bf0.v, acc0, 0, 0, 0);
    acc1 = __builtin_amdgcn_mfma_f32_16x16x32_bf16(af.v, bf1.v, acc1, 0, 0, 0);
  }
  *(f32x4*)(&red[((w * 2 + 0) * 64 + l) * 4]) = acc0;
  *(f32x4*)(&red[((w * 2 + 1) * 64 + l) * 4]) = acc1;
  __syncthreads();
#pragma unroll
  for (int u = 0; u < 2; ++u) {
    const int o = tid + u * 256;
    const int rr = o >> 5, h = o & 31;
    const int tt = h >> 4, mm = h & 15;
    const int ll = ((rr >> 2) << 4) | mm, r = rr & 3;
    float sum = red[(0 + tt) * 256 + ll * 4 + r] + red[(2 + tt) * 256 + ll * 4 + r] +
                red[(4 + tt) * 256 + ll * 4 + r] + red[(6 + tt) * 256 + ll * 4 + r];
    if (isq) sum += b1[h];
    E[(size_t)(row0 + rr) * HH + h] = fexp2(S * sum);
  }
}

__global__ __launch_bounds__(256) void p1_proj_mfma(
    const float* __restrict__ keys, const float* __restrict__ queries,
    const float* __restrict__ W1, const float* __restrict__ b1,
    float* __restrict__ E) {
  p1_body(keys, queries, W1, b1, E, blockIdx.x * 16);
}

// PROBE: 24 identical copies of p1's full work, disjoint ws outputs.
__global__ __launch_bounds__(256) void p1_probe(
    const float* __restrict__ keys, const float* __restrict__ queries,
    const float* __restrict__ W1, const float* __restrict__ b1,
    float* __restrict__ Eprobe) {
  float* E = Eprobe + (size_t)blockIdx.y * 4096 * HH;
  p1_body(keys, queries, W1, b1, E, blockIdx.x * 16);
}

// ---------------- p2 body (R9, unchanged) ----------------
static __device__ __forceinline__ void p2_body(
    const float* __restrict__ E, const float* __restrict__ W2,
    const float* __restrict__ b2, float* __restrict__ out, int b) {
  const int tid = threadIdx.x;
  const int kl = tid & 63;
  const int qg = __builtin_amdgcn_readfirstlane(tid >> 6);  // wave-uniform
  const int k0 = blockIdx.x * 64, q0 = blockIdx.y * 32;
  float w2v[HH];  // SGPR-resident raw weights
  float c0 = rfl_f32(b2[0]);
#pragma unroll
  for (int h = 0; h < HH; ++h) {
    w2v[h] = rfl_f32(W2[h]);
    c0 += w2v[h];
  }
  const float* ekp = E + (size_t)(b * NKS + k0 + kl) * HH;
  float acc[8];
#pragma unroll
  for (int j = 0; j < 8; ++j) acc[j] = c0;
#pragma unroll
  for (int half = 0; half < 2; ++half) {
    float ek[16];
#pragma unroll
    for (int i = 0; i < 4; ++i) {
      float4 v = *(const float4*)(ekp + half * 16 + i * 4);
      ek[i * 4 + 0] = v.x; ek[i * 4 + 1] = v.y;
      ek[i * 4 + 2] = v.z; ek[i * 4 + 3] = v.w;
    }
    const float* eqb =
        E + ((size_t)NKROW + (size_t)b * NQS + q0 + qg * 8) * HH + half * 16;
#pragma unroll
    for (int j = 0; j < 8; ++j) {
      const float* ej = eqb + (size_t)j * HH;  // uniform -> s_load
      float a0 = 0.f, a1 = 0.f;
#pragma unroll
      for (int i2 = 0; i2 < 4; ++i2) {
        float4 ev = *(const float4*)(ej + i2 * 4);
        const int hb = half * 16 + i2 * 4;
        {
          float da = fmaf(ek[i2 * 4 + 0], ev.x, 1.f);
          float db = fmaf(ek[i2 * 4 + 1], ev.y, 1.f);
          float num = fmaf(w2v[hb + 0], db, w2v[hb + 1] * da);
          a0 = fmaf(num, frcp(da * db), a0);
        }
        {
          float da = fmaf(ek[i2 * 4 + 2], ev.z, 1.f);
          float db = fmaf(ek[i2 * 4 + 3], ev.w, 1.f);
          float num = fmaf(w2v[hb + 2], db, w2v[hb + 3] * da);
          a1 = fmaf(num, frcp(da * db), a1);
        }
      }
      acc[j] += a0 + a1;
    }
  }
  float* outp = out + ((size_t)b * NQS + q0 + qg * 8) * NKS + k0 + kl;
#pragma unroll
  for (int j = 0; j < 8; ++j) outp[(size_t)j * NKS] = fmaf(-2.f, acc[j] - c0, c0);
}

__global__ __launch_bounds__(256, 4) void p2_score(
    const float* __restrict__ E, const float* __restrict__ W2,
    const float* __restrict__ b2, float* __restrict__ out) {
  p2_body(E, W2, b2, out, blockIdx.z);
}

// PROBE: 4 identical copies of p2's full work, disjoint ws outputs.
__global__ __launch_bounds__(256, 4) void p2_probe(
    const float* __restrict__ E, const float* __restrict__ W2,
    const float* __restrict__ b2, float* __restrict__ outprobe) {
  const int copy = blockIdx.z >> 1, b = blockIdx.z & 1;
  float* out = outprobe + (size_t)copy * NB * NQS * NKS;
  p2_body(E, W2, b2, out, b);
}

extern "C" void kernel_launch(void* const* d_in, const int* in_sizes, int n_in,
                              void* d_out, int out_size, void* d_ws, size_t ws_size,
                              hipStream_t stream) {
  const float* keys = (const float*)d_in[0];
  const float* queries = (const float*)d_in[1];
  const float* W1 = (const float*)d_in[2];
  const float* b1 = (const float*)d_in[3];
  const float* W2 = (const float*)d_in[4];
  const float* b2 = (const float*)d_in[5];
  float* out = (float*)d_out;
  float* ws = (float*)d_ws;
  float* E = ws;                             // [4096][32] = 512 KB
  float* probe2_out = ws + (size_t)4 * 1024 * 1024;   // 4 copies x 8.4 MB
  float* probe1_out = ws + (size_t)16 * 1024 * 1024;  // 24 copies x 512 KB

  // production p1 (R9)
  hipLaunchKernelGGL(p1_proj_mfma, dim3(256), dim3(256), 0, stream,
                     keys, queries, W1, b1, E);
  // probe: 24x p1 in one dispatch (idempotent, disjoint outputs)
  hipLaunchKernelGGL(p1_probe, dim3(256, 24), dim3(256), 0, stream,
                     keys, queries, W1, b1, probe1_out);
  // probe: 4x p2 in one dispatch (reads real E, disjoint outputs)
  hipLaunchKernelGGL(p2_probe, dim3(NKS / 64, NQS / 32, NB * 4), dim3(256), 0,
                     stream, E, W2, b2, probe2_out);
  // production p2 (R9) -- last, writes final out
  hipLaunchKernelGGL(p2_score, dim3(NKS / 64, NQS / 32, NB), dim3(256), 0, stream,
                     E, W2, b2, out);
}

// Round 12
// 24.337 us; speedup vs baseline: 3.7007x; 3.7007x over previous
//
#include <hip/hip_runtime.h>
#include <hip/hip_bf16.h>

#define NB 2
#define NQS 1024
#define NKS 1024
#define DD 512
#define HH 32
#define NKROW (NB * NKS)  // 2048 key rows; query rows follow in E
#define W1S 34            // LDS stride: conflict-free B-frag reads

typedef __attribute__((ext_vector_type(8))) short bf16x8;
typedef __attribute__((ext_vector_type(4))) float f32x4;

static __device__ __forceinline__ float fexp2(float x) {
#if __has_builtin(__builtin_amdgcn_exp2f)
  return __builtin_amdgcn_exp2f(x);
#else
  float r; asm("v_exp_f32 %0, %1" : "=v"(r) : "v"(x)); return r;
#endif
}
static __device__ __forceinline__ float frcp(float x) {
#if __has_builtin(__builtin_amdgcn_rcpf)
  return __builtin_amdgcn_rcpf(x);
#else
  float r; asm("v_rcp_f32 %0, %1" : "=v"(r) : "v"(x)); return r;
#endif
}
// readfirstlane preserving float bits (builtin is int-typed)
static __device__ __forceinline__ float rfl_f32(float x) {
  return __int_as_float(__builtin_amdgcn_readfirstlane(__float_as_int(x)));
}

// p1a: partial projections. Grid = 1024 blocks: (row-tile rt 0..255) x (kchunk
// kc 0..3). Block stages W1[kc*128..+128) (16 KB fp32 -> 8.7 KB bf16 LDS) and
// computes 16 rows x 32 h partial sums over K=128 (4 waves x K=32 each),
// reduced block-locally. Writes f32 partials (no bias/exp2).
// 4 blocks/CU resident -> latency hidden (R11 probe evidence).
__global__ __launch_bounds__(256) void p1a_partial(
    const float* __restrict__ keys, const float* __restrict__ queries,
    const float* __restrict__ W1, float* __restrict__ Epart) {
  __shared__ __hip_bfloat16 W1L[128 * W1S];  // 8704 B
  __shared__ float red[4 * 2 * 64 * 4];      // 8192 B
  const int tid = threadIdx.x;
  const int rt = blockIdx.x >> 2, kc = blockIdx.x & 3;
  const int row0 = rt * 16;
  const bool isq = row0 >= NKROW;
  const float* src = isq ? queries + (size_t)(row0 - NKROW) * DD
                         : keys + (size_t)row0 * DD;
  const float* w1 = W1 + (isq ? (size_t)DD * HH : 0) + (size_t)kc * 128 * HH;
  // stage 128x32 fp32 -> bf16 LDS stride-34 (1024 float4s, 4 per thread)
#pragma unroll
  for (int s = 0; s < 4; ++s) {
    const int f = tid + s * 256;
    float4 v = *(const float4*)(w1 + (size_t)f * 4);
    const int k = f >> 3, h0 = (f & 7) * 4;
    __hip_bfloat16* p = &W1L[k * W1S + h0];
    p[0] = __float2bfloat16(v.x); p[1] = __float2bfloat16(v.y);
    p[2] = __float2bfloat16(v.z); p[3] = __float2bfloat16(v.w);
  }
  __syncthreads();
  const int l = tid & 63, w = tid >> 6;  // wave w = k-substep
  const int m = l & 15, kq = l >> 4;
  union Frag { bf16x8 v; __hip_bfloat16 e[8]; };
  // A: row m, k = kc*128 + w*32 + kq*8 + j
  const float* arow = src + (size_t)m * DD + kc * 128 + w * 32 + kq * 8;
  float4 a0 = *(const float4*)(arow);
  float4 a1 = *(const float4*)(arow + 4);
  Frag af, bf0, bf1;
  af.e[0] = __float2bfloat16(a0.x); af.e[1] = __float2bfloat16(a0.y);
  af.e[2] = __float2bfloat16(a0.z); af.e[3] = __float2bfloat16(a0.w);
  af.e[4] = __float2bfloat16(a1.x); af.e[5] = __float2bfloat16(a1.y);
  af.e[6] = __float2bfloat16(a1.z); af.e[7] = __float2bfloat16(a1.w);
  const __hip_bfloat16* bp = &W1L[(w * 32 + kq * 8) * W1S + m];
#pragma unroll
  for (int j = 0; j < 8; ++j) {
    bf0.e[j] = bp[j * W1S];
    bf1.e[j] = bp[j * W1S + 16];
  }
  f32x4 z = {0.f, 0.f, 0.f, 0.f};
  f32x4 acc0 = __builtin_amdgcn_mfma_f32_16x16x32_bf16(af.v, bf0.v, z, 0, 0, 0);
  f32x4 acc1 = __builtin_amdgcn_mfma_f32_16x16x32_bf16(af.v, bf1.v, z, 0, 0, 0);
  *(f32x4*)(&red[((w * 2 + 0) * 64 + l) * 4]) = acc0;
  *(f32x4*)(&red[((w * 2 + 1) * 64 + l) * 4]) = acc1;
  __syncthreads();
  // block-reduce 4 waves -> 512 outputs (16 rows x 32 h), 2 per thread
#pragma unroll
  for (int u = 0; u < 2; ++u) {
    const int o = tid + u * 256;
    const int rr = o >> 5, h = o & 31;
    const int tt = h >> 4, mm = h & 15;
    const int ll = ((rr >> 2) << 4) | mm, r = rr & 3;
    float sum = red[(0 + tt) * 256 + ll * 4 + r] + red[(2 + tt) * 256 + ll * 4 + r] +
                red[(4 + tt) * 256 + ll * 4 + r] + red[(6 + tt) * 256 + ll * 4 + r];
    Epart[((size_t)kc * 4096 + row0 + rr) * HH + h] = sum;
  }
}

// p1b: E[row][h] = exp2(S * (sum_kc Epart + (isq? b1 : 0))). 512 blocks.
__global__ __launch_bounds__(256) void p1b_finish(
    const float* __restrict__ Epart, const float* __restrict__ b1,
    float* __restrict__ E) {
  const float S = 2.8853900817779268f;  // 2*log2(e)
  const int o = blockIdx.x * 256 + threadIdx.x;
  const int row = o >> 5, h = o & 31;
  float sum = Epart[(size_t)o] + Epart[(size_t)o + 4096 * HH] +
              Epart[(size_t)o + 2 * 4096 * HH] + Epart[(size_t)o + 3 * 4096 * HH];
  if (row >= NKROW) sum += b1[h];
  E[(size_t)o] = fexp2(S * sum);
}

// p2 (register-lean R9 body, q-tile 16): logit = c0 - 2*sum_h w_h*rcp(1+ek*eq),
// pair-merged; W2 in SGPRs (bit-cast readfirstlane, no VALU math on them).
// Grid 2048 = 8 blocks/CU, acc[4], ~40 VGPR.
__global__ __launch_bounds__(256, 4) void p2_score(
    const float* __restrict__ E, const float* __restrict__ W2,
    const float* __restrict__ b2, float* __restrict__ out) {
  const int tid = threadIdx.x;
  const int kl = tid & 63;
  const int qg = __builtin_amdgcn_readfirstlane(tid >> 6);  // wave-uniform
  const int k0 = blockIdx.x * 64, q0 = blockIdx.y * 16, b = blockIdx.z;
  float w2v[HH];  // SGPR-resident raw weights
  float c0 = rfl_f32(b2[0]);
#pragma unroll
  for (int h = 0; h < HH; ++h) {
    w2v[h] = rfl_f32(W2[h]);
    c0 += w2v[h];
  }
  const float* ekp = E + (size_t)(b * NKS + k0 + kl) * HH;
  float acc[4] = {0.f, 0.f, 0.f, 0.f};
#pragma unroll
  for (int half = 0; half < 2; ++half) {
    float ek[16];
#pragma unroll
    for (int i = 0; i < 4; ++i) {
      float4 v = *(const float4*)(ekp + half * 16 + i * 4);
      ek[i * 4 + 0] = v.x; ek[i * 4 + 1] = v.y;
      ek[i * 4 + 2] = v.z; ek[i * 4 + 3] = v.w;
    }
    const float* eqb =
        E + ((size_t)NKROW + (size_t)b * NQS + q0 + qg * 4) * HH + half * 16;
#pragma unroll
    for (int j = 0; j < 4; ++j) {
      const float* ej = eqb + (size_t)j * HH;  // uniform -> s_load
      float a0 = 0.f, a1 = 0.f;
#pragma unroll
      for (int i2 = 0; i2 < 4; ++i2) {
        float4 ev = *(const float4*)(ej + i2 * 4);
        const int hb = half * 16 + i2 * 4;
        {
          float da = fmaf(ek[i2 * 4 + 0], ev.x, 1.f);
          float db = fmaf(ek[i2 * 4 + 1], ev.y, 1.f);
          float num = fmaf(w2v[hb + 0], db, w2v[hb + 1] * da);
          a0 = fmaf(num, frcp(da * db), a0);
        }
        {
          float da = fmaf(ek[i2 * 4 + 2], ev.z, 1.f);
          float db = fmaf(ek[i2 * 4 + 3], ev.w, 1.f);
          float num = fmaf(w2v[hb + 2], db, w2v[hb + 3] * da);
          a1 = fmaf(num, frcp(da * db), a1);
        }
      }
      acc[j] += a0 + a1;
    }
  }
  float* outp = out + ((size_t)b * NQS + q0 + qg * 4) * NKS + k0 + kl;
#pragma unroll
  for (int j = 0; j < 4; ++j) outp[(size_t)j * NKS] = fmaf(-2.f, acc[j], c0);
}

extern "C" void kernel_launch(void* const* d_in, const int* in_sizes, int n_in,
                              void* d_out, int out_size, void* d_ws, size_t ws_size,
                              hipStream_t stream) {
  const float* keys = (const float*)d_in[0];
  const float* queries = (const float*)d_in[1];
  const float* W1 = (const float*)d_in[2];
  const float* b1 = (const float*)d_in[3];
  const float* W2 = (const float*)d_in[4];
  const float* b2 = (const float*)d_in[5];
  float* out = (float*)d_out;
  float* ws = (float*)d_ws;
  float* E = ws;                        // [4096][32] f32 = 512 KB
  float* Epart = ws + 1024 * 1024;      // [4][4096][32] f32 = 2 MB

  hipLaunchKernelGGL(p1a_partial, dim3(1024), dim3(256), 0, stream,
                     keys, queries, W1, Epart);
  hipLaunchKernelGGL(p1b_finish, dim3(512), dim3(256), 0, stream,
                     Epart, b1, E);
  hipLaunchKernelGGL(p2_score, dim3(NKS / 64, NQS / 16, NB), dim3(256), 0, stream,
                     E, W2, b2, out);
}